// Round 27
// baseline (60.174 us; speedup 1.0000x reference)
//
#include <hip/hip_runtime.h>
#include <hip/hip_bf16.h>

#define B 2
#define S 2048
#define E 128
#define H 8
#define HD 16
#define BH (B*H)

#define RPB 8    // rows per block (qkv_proj)
#define KT 128   // key tile (attn)

typedef __attribute__((ext_vector_type(8))) short bf16x8;
typedef __attribute__((ext_vector_type(4))) float f32x4;

__device__ __forceinline__ unsigned short f2b(float f) {   // f32->bf16 RNE
    const unsigned u = __float_as_uint(f);
    return (unsigned short)((u + 0x7FFFu + ((u >> 16) & 1u)) >> 16);
}
__device__ __forceinline__ float b2f(unsigned short u) {
    return __uint_as_float((unsigned)u << 16);
}

// ---- Pass A: order-preserving mask compaction (1 wave per batch). ----
__global__ __launch_bounds__(64) void compact_idx(
    const int* __restrict__ mask, const int* __restrict__ masked_p,
    int* __restrict__ pos, int* __restrict__ cnt)
{
    const int b = blockIdx.x, lane = threadIdx.x;
    const int masked = *masked_p;
    int v[32];
    #pragma unroll
    for (int c = 0; c < 32; ++c)
        v[c] = mask[b * S + c * 64 + lane];

    int base = 0;
    #pragma unroll
    for (int c = 0; c < 32; ++c) {
        const bool keep = (masked != 0) || (v[c] != 0);
        const unsigned long long bal = __ballot(keep);
        const int my = base + (int)__popcll(bal & ((1ULL << lane) - 1ULL));
        pos[b * S + c * 64 + lane] = keep ? my : -1;
        base += (int)__popcll(bal);
    }
    if (base == 0) {                       // all masked: -1000 shift cancels
        #pragma unroll
        for (int c = 0; c < 32; ++c)
            pos[b * S + c * 64 + lane] = c * 64 + lane;
        base = S;
    }
    if (lane == 0) cnt[b] = base;
}

// ---- Pass B: zero ragged tail rows of Kx/Bt (guard vs stale Inf/NaN). ----
__global__ __launch_bounds__(64) void zero_tail(
    const int* __restrict__ cnt,
    unsigned short* __restrict__ Kxg, unsigned short* __restrict__ Btg)
{
    const int bh = blockIdx.x, b = bh >> 3;
    const int cn = cnt[b];
    const int pad = ((cn + KT - 1) / KT) * KT;
    const int nrows = pad - cn;
    unsigned short* KxB = Kxg + (size_t)bh * S * 32;
    unsigned short* BtB = Btg + (size_t)bh * S * 32;
    for (int idx = threadIdx.x; idx < nrows * 16; idx += 64) {
        const int row = cn + (idx >> 4), d = idx & 15;
        KxB[row * 32 + d]      = 0;
        KxB[row * 32 + 16 + d] = 0;
        BtB[((row >> 4) * 16 + d) * 32 + (row & 15)]      = 0;
        BtB[((row >> 4) * 16 + d) * 32 + (row & 15) + 16] = 0;
    }
}

// ---- Pass 0: QKV projection; K/V written compacted, MFMA-ready bf16. ----
__global__ __launch_bounds__(128) void qkv_proj(
    const float* __restrict__ x,
    const float* __restrict__ wq,
    const float* __restrict__ wk,
    const float* __restrict__ wv,
    const int* __restrict__ pos,
    float* __restrict__ Q,
    unsigned short* __restrict__ Kxg, unsigned short* __restrict__ Btg)
{
    __shared__ float xs[RPB][E];
    const int row0 = blockIdx.x * RPB;
    const int c    = threadIdx.x;
    #pragma unroll
    for (int rr = 0; rr < RPB; ++rr)
        xs[rr][c] = x[(size_t)(row0 + rr) * E + c];
    __syncthreads();

    float aq[RPB], ak[RPB], av[RPB];
    #pragma unroll
    for (int rr = 0; rr < RPB; ++rr) { aq[rr] = 0.f; ak[rr] = 0.f; av[rr] = 0.f; }

    for (int i = 0; i < E; ++i) {
        const float wqv = wq[i * E + c];
        const float wkv = wk[i * E + c];
        const float wvv = wv[i * E + c];
        #pragma unroll
        for (int rr = 0; rr < RPB; ++rr) {
            const float xv = xs[rr][i];
            aq[rr] = fmaf(xv, wqv, aq[rr]);
            ak[rr] = fmaf(xv, wkv, ak[rr]);
            av[rr] = fmaf(xv, wvv, av[rr]);
        }
    }

    const int h = c & 7, d = c >> 3;       // faithful split: col = d*8+h
    #pragma unroll
    for (int rr = 0; rr < RPB; ++rr) {
        const int row = row0 + rr;
        const int b = row >> 11, s = row & 2047;
        const int bh = b * H + h;
        Q[(((size_t)bh) * S + s) * HD + d] = aq[rr] * 0.25f;
        const int p_ = pos[row];
        if (p_ >= 0) {
            const unsigned short kh = f2b(ak[rr]);
            const unsigned short kl = f2b(ak[rr] - b2f(kh));
            const unsigned short vh = f2b(av[rr]);
            const unsigned short vl = f2b(av[rr] - b2f(vh));
            unsigned short* kx = Kxg + (size_t)bh * S * 32 + (size_t)p_ * 32;
            kx[d]      = kh;
            kx[16 + d] = kl;
            unsigned short* bt = Btg + (size_t)bh * S * 32
                               + ((size_t)(p_ >> 4) * 16 + d) * 32 + (p_ & 15);
            bt[0]  = vh;
            bt[16] = vl;
        }
    }
}

// ---- Pass 1: MFMA flash attention, key-split across 2 waves. ----
// Block 128 = 2 waves on the SAME 16 queries; wave w does tiles w, w+2, ...
// Grid (S/16, BH) = 2048 blocks -> 4 waves/SIMD. LDS merge at end.
__global__ __launch_bounds__(128) void attn(
    const float* __restrict__ Q,
    const unsigned short* __restrict__ Kxg,
    const unsigned short* __restrict__ Btg,
    const int* __restrict__ cnt,
    float* __restrict__ out)
{
    __shared__ float Lm[16], Ll[16];
    __shared__ f32x4 Lacc[64];

    const int bh    = blockIdx.y;
    const int b     = bh >> 3;
    const int h     = bh & 7;
    const int qg16  = blockIdx.x;        // 0..127
    const int tid   = threadIdx.x;       // 0..127
    const int wid   = tid >> 6;
    const int lane  = tid & 63;
    const int col   = lane & 15;
    const int g     = lane >> 4;         // 0..3
    const int qrow0 = qg16 * 16;
    const int cn    = cnt[b];
    const int nt    = (cn + KT - 1) >> 7;

    const unsigned short* KxB = Kxg + (size_t)bh * S * 32;
    const unsigned short* BtB = Btg + (size_t)bh * S * 32;

    // Q B-frags (hi, lo); 0.25 pre-folded. Lane supplies dims 8*(g&1)..+7.
    bf16x8 qh, ql;
    {
        const float* qp = Q + ((size_t)bh * S + qrow0 + col) * HD + 8 * (g & 1);
        #pragma unroll
        for (int i = 0; i < 8; ++i) {
            const float f = qp[i];
            const unsigned short hi = f2b(f);
            qh[i] = (short)hi;
            ql[i] = (short)f2b(f - b2f(hi));
        }
    }

    float m = -1e30f, l = 0.f;           // l: per-lane partial (this lane's keys)
    f32x4 acc = {0.f, 0.f, 0.f, 0.f};

    for (int kt = wid; kt < nt; kt += 2) {
        const int base = kt * KT;

        // ---- phase A: scores^T via 2 MFMAs per 16-key block ----
        f32x4 sc[8];
        #pragma unroll
        for (int kb = 0; kb < 8; ++kb) {
            const bf16x8 ka = *(const bf16x8*)(
                KxB + (size_t)(base + kb * 16 + col) * 32 + 8 * g);
            f32x4 c = {0.f, 0.f, 0.f, 0.f};
            c = __builtin_amdgcn_mfma_f32_16x16x32_bf16(ka, qh, c, 0, 0, 0);
            c = __builtin_amdgcn_mfma_f32_16x16x32_bf16(ka, ql, c, 0, 0, 0);
            sc[kb] = c;
        }
        if (base + KT > cn) {                 // tail: mask fake keys
            #pragma unroll
            for (int kb = 0; kb < 8; ++kb)
                #pragma unroll
                for (int r = 0; r < 4; ++r)
                    if (base + kb * 16 + 4 * g + r >= cn) sc[kb][r] = -1e30f;
        }

        // ---- phase B: tile max per query col; skip rescale if max unmoved --
        float tm = sc[0][0];
        #pragma unroll
        for (int kb = 0; kb < 8; ++kb)
            #pragma unroll
            for (int r = 0; r < 4; ++r) tm = fmaxf(tm, sc[kb][r]);
        tm = fmaxf(tm, __shfl_xor(tm, 16));
        tm = fmaxf(tm, __shfl_xor(tm, 32));
        if (__any(tm > m)) {
            const float mn = fmaxf(m, tm);
            const float alpha = __expf(m - mn);   // m=-1e30 first tile -> 0
            m = mn;
            l *= alpha;
            #pragma unroll
            for (int r = 0; r < 4; ++r)
                acc[r] *= __shfl(alpha, 4 * g + r);
        }

        // ---- phase C: exp, pack, redistribute, PV MFMA (no l shuffles) ----
        #pragma unroll
        for (int kb = 0; kb < 8; ++kb) {
            const float p0 = __expf(sc[kb][0] - m);
            const float p1 = __expf(sc[kb][1] - m);
            const float p2 = __expf(sc[kb][2] - m);
            const float p3 = __expf(sc[kb][3] - m);
            l += (p0 + p1) + (p2 + p3);

            const unsigned u01 = (unsigned)f2b(p0) | ((unsigned)f2b(p1) << 16);
            const unsigned u23 = (unsigned)f2b(p2) | ((unsigned)f2b(p3) << 16);
            const int s0 = col + 16 * (2 * (g & 1));
            const int s1 = s0 + 16;
            union { unsigned u[4]; bf16x8 v; } pa;
            pa.u[0] = (unsigned)__shfl((int)u01, s0);
            pa.u[1] = (unsigned)__shfl((int)u23, s0);
            pa.u[2] = (unsigned)__shfl((int)u01, s1);
            pa.u[3] = (unsigned)__shfl((int)u23, s1);

            const bf16x8 vb = *(const bf16x8*)(
                BtB + (size_t)((base >> 4) + kb) * 512 + col * 32 + 8 * g);
            acc = __builtin_amdgcn_mfma_f32_16x16x32_bf16(pa.v, vb, acc, 0, 0, 0);
        }
    }

    // ---- per-wave: reduce l across the 4 g-groups (per query col) ----
    l += __shfl_xor(l, 16);
    l += __shfl_xor(l, 32);

    // ---- cross-wave merge via LDS ----
    if (wid == 1) {
        if (g == 0) { Lm[col] = m; Ll[col] = l; }
        Lacc[lane] = acc;
    }
    __syncthreads();
    if (wid == 0) {
        const float m1 = Lm[col];
        const float l1 = Ll[col];
        const f32x4 acc1 = Lacc[lane];
        const float mn = fmaxf(m, m1);
        const float a0 = __expf(m - mn);
        const float a1 = __expf(m1 - mn);
        const float ltot = l * a0 + l1 * a1;
        const float inv = 1.f / ltot;         // per query col
        #pragma unroll
        for (int r = 0; r < 4; ++r) {
            const float b0 = __shfl(a0, 4 * g + r);
            const float b1 = __shfl(a1, 4 * g + r);
            const float ir = __shfl(inv, 4 * g + r);
            const float v = (acc[r] * b0 + acc1[r] * b1) * ir;
            // faithful d8h merge: out[b][q][dim*8+h]
            out[((size_t)(b * S + qrow0 + 4 * g + r)) * E + col * 8 + h] = v;
        }
    }
}

extern "C" void kernel_launch(void* const* d_in, const int* in_sizes, int n_in,
                              void* d_out, int out_size, void* d_ws, size_t ws_size,
                              hipStream_t stream) {
    int ix = 0, im0 = -1, isc = -1, iw[3] = {-1, -1, -1}, nw = 0;
    for (int i = 0; i < n_in; ++i) {
        const int sz = in_sizes[i];
        if (sz == B * S * E) ix = i;
        else if (sz == B * S) { if (im0 < 0) im0 = i; }
        else if (sz == E * E) { if (nw < 3) iw[nw++] = i; }
        else if (sz == 1 && isc < 0) isc = i;
    }
    if (im0 < 0) im0 = 1;
    if (isc < 0) isc = 3;
    if (nw < 3) { iw[0] = n_in - 3; iw[1] = n_in - 2; iw[2] = n_in - 1; }

    const float* x        = (const float*)d_in[ix];
    const int*   src_mask = (const int*)d_in[im0];
    const int*   masked_p = (const int*)d_in[isc];
    const float* wq       = (const float*)d_in[iw[0]];
    const float* wk       = (const float*)d_in[iw[1]];
    const float* wv       = (const float*)d_in[iw[2]];
    float*       out      = (float*)d_out;

    float*          Qw  = (float*)d_ws;
    unsigned short* Kxg = (unsigned short*)(Qw + (size_t)BH * S * HD);
    unsigned short* Btg = Kxg + (size_t)BH * S * 32;
    int*            pos = (int*)(Btg + (size_t)BH * S * 32);
    int*            cnt = pos + B * S;

    compact_idx<<<B, 64, 0, stream>>>(src_mask, masked_p, pos, cnt);
    zero_tail<<<BH, 64, 0, stream>>>(cnt, Kxg, Btg);
    qkv_proj<<<B * S / RPB, 128, 0, stream>>>(x, wq, wk, wv, pos, Qw, Kxg, Btg);
    attn<<<dim3(S / 16, BH), 128, 0, stream>>>(Qw, Kxg, Btg, cnt, out);
}

// Round 28
// 52.015 us; speedup vs baseline: 1.1569x; 1.1569x over previous
//
#include <hip/hip_runtime.h>
#include <hip/hip_bf16.h>

#define B 2
#define S 2048
#define E 128
#define H 8
#define HD 16
#define BH (B*H)

#define RPB 8    // rows per block (qkv_proj)
#define KT 128   // key tile (attn)

typedef __attribute__((ext_vector_type(8))) short bf16x8;
typedef __attribute__((ext_vector_type(4))) float f32x4;

__device__ __forceinline__ unsigned short f2b(float f) {   // f32->bf16 RNE
    const unsigned u = __float_as_uint(f);
    return (unsigned short)((u + 0x7FFFu + ((u >> 16) & 1u)) >> 16);
}
__device__ __forceinline__ float b2f(unsigned short u) {
    return __uint_as_float((unsigned)u << 16);
}

// ---- Pass A: compaction + tail-zero fused. Grid BH x 64 threads. ----
// Every block recomputes its batch's keep-scan (cheap); h==0 blocks write
// pos/cnt; ALL blocks zero their own bh's ragged tail rows of Kx/Bt.
__global__ __launch_bounds__(64) void prep(
    const int* __restrict__ mask, const int* __restrict__ masked_p,
    int* __restrict__ pos, int* __restrict__ cnt,
    unsigned short* __restrict__ Kxg, unsigned short* __restrict__ Btg)
{
    const int bh = blockIdx.x;
    const int b = bh >> 3, h = bh & 7;
    const int lane = threadIdx.x;
    const int masked = *masked_p;

    int v[32];
    #pragma unroll
    for (int c = 0; c < 32; ++c)
        v[c] = mask[b * S + c * 64 + lane];

    int base = 0;
    #pragma unroll
    for (int c = 0; c < 32; ++c) {
        const bool keep = (masked != 0) || (v[c] != 0);
        const unsigned long long bal = __ballot(keep);
        if (h == 0) {
            const int my = base + (int)__popcll(bal & ((1ULL << lane) - 1ULL));
            pos[b * S + c * 64 + lane] = keep ? my : -1;
        }
        base += (int)__popcll(bal);
    }
    int cn = base;
    if (cn == 0) {                         // all masked: -1000 shift cancels
        if (h == 0) {
            #pragma unroll
            for (int c = 0; c < 32; ++c)
                pos[b * S + c * 64 + lane] = c * 64 + lane;
        }
        cn = S;
    }
    if (h == 0 && lane == 0) cnt[b] = cn;

    // zero this bh's tail rows
    const int pad = ((cn + KT - 1) / KT) * KT;
    const int nrows = pad - cn;
    unsigned short* KxB = Kxg + (size_t)bh * S * 32;
    unsigned short* BtB = Btg + (size_t)bh * S * 32;
    for (int idx = lane; idx < nrows * 16; idx += 64) {
        const int row = cn + (idx >> 4), d = idx & 15;
        KxB[row * 32 + d]      = 0;
        KxB[row * 32 + 16 + d] = 0;
        BtB[((row >> 4) * 16 + d) * 32 + (row & 15)]      = 0;
        BtB[((row >> 4) * 16 + d) * 32 + (row & 15) + 16] = 0;
    }
}

// ---- Pass 0: QKV projection; K/V written compacted, MFMA-ready bf16. ----
__global__ __launch_bounds__(128) void qkv_proj(
    const float* __restrict__ x,
    const float* __restrict__ wq,
    const float* __restrict__ wk,
    const float* __restrict__ wv,
    const int* __restrict__ pos,
    float* __restrict__ Q,
    unsigned short* __restrict__ Kxg, unsigned short* __restrict__ Btg)
{
    __shared__ float xs[RPB][E];
    const int row0 = blockIdx.x * RPB;
    const int c    = threadIdx.x;
    #pragma unroll
    for (int rr = 0; rr < RPB; ++rr)
        xs[rr][c] = x[(size_t)(row0 + rr) * E + c];
    __syncthreads();

    float aq[RPB], ak[RPB], av[RPB];
    #pragma unroll
    for (int rr = 0; rr < RPB; ++rr) { aq[rr] = 0.f; ak[rr] = 0.f; av[rr] = 0.f; }

    for (int i = 0; i < E; ++i) {
        const float wqv = wq[i * E + c];
        const float wkv = wk[i * E + c];
        const float wvv = wv[i * E + c];
        #pragma unroll
        for (int rr = 0; rr < RPB; ++rr) {
            const float xv = xs[rr][i];
            aq[rr] = fmaf(xv, wqv, aq[rr]);
            ak[rr] = fmaf(xv, wkv, ak[rr]);
            av[rr] = fmaf(xv, wvv, av[rr]);
        }
    }

    const int h = c & 7, d = c >> 3;       // faithful split: col = d*8+h
    #pragma unroll
    for (int rr = 0; rr < RPB; ++rr) {
        const int row = row0 + rr;
        const int b = row >> 11, s = row & 2047;
        const int bh = b * H + h;
        Q[(((size_t)bh) * S + s) * HD + d] = aq[rr] * 0.25f;
        const int p_ = pos[row];
        if (p_ >= 0) {
            const unsigned short kh = f2b(ak[rr]);
            const unsigned short kl = f2b(ak[rr] - b2f(kh));
            const unsigned short vh = f2b(av[rr]);
            const unsigned short vl = f2b(av[rr] - b2f(vh));
            unsigned short* kx = Kxg + (size_t)bh * S * 32 + (size_t)p_ * 32;
            kx[d]      = kh;
            kx[16 + d] = kl;
            unsigned short* bt = Btg + (size_t)bh * S * 32
                               + ((size_t)(p_ >> 4) * 16 + d) * 32 + (p_ & 15);
            bt[0]  = vh;
            bt[16] = vl;
        }
    }
}

// ---- Pass 1: MFMA flash attention, 2-deep software-pipelined loads. ----
// Block 128 = 2 independent waves; wave handles 16 queries, all keys.
// Fragments direct from global (L2); next tile's 16 loads issued before
// computing the current tile (double-buffered registers).
__global__ __launch_bounds__(128) void attn(
    const float* __restrict__ Q,
    const unsigned short* __restrict__ Kxg,
    const unsigned short* __restrict__ Btg,
    const int* __restrict__ cnt,
    float* __restrict__ out)
{
    const int bh    = blockIdx.y;
    const int b     = bh >> 3;
    const int h     = bh & 7;
    const int qtile = blockIdx.x;        // 0..63
    const int tid   = threadIdx.x;       // 0..127
    const int wid   = tid >> 6;
    const int lane  = tid & 63;
    const int col   = lane & 15;
    const int g     = lane >> 4;         // 0..3
    const int qrow0 = qtile * 32 + wid * 16;
    const int cn    = cnt[b];
    const int nt    = (cn + KT - 1) >> 7;

    const unsigned short* KxB = Kxg + (size_t)bh * S * 32;
    const unsigned short* BtB = Btg + (size_t)bh * S * 32;

    // Q B-frags (hi, lo); 0.25 pre-folded. Lane supplies dims 8*(g&1)..+7.
    bf16x8 qh, ql;
    {
        const float* qp = Q + ((size_t)bh * S + qrow0 + col) * HD + 8 * (g & 1);
        #pragma unroll
        for (int i = 0; i < 8; ++i) {
            const float f = qp[i];
            const unsigned short hi = f2b(f);
            qh[i] = (short)hi;
            ql[i] = (short)f2b(f - b2f(hi));
        }
    }

    float m = -1e30f, l = 0.f;
    f32x4 acc = {0.f, 0.f, 0.f, 0.f};

#define LOADT(KA, VB, TBASE)                                              \
    {                                                                     \
        const int base_ = (TBASE);                                        \
        _Pragma("unroll")                                                 \
        for (int kb = 0; kb < 8; ++kb) {                                  \
            KA[kb] = *(const bf16x8*)(                                    \
                KxB + (size_t)(base_ + kb * 16 + col) * 32 + 8 * g);      \
            VB[kb] = *(const bf16x8*)(                                    \
                BtB + (size_t)((base_ >> 4) + kb) * 512 + col * 32 + 8 * g); \
        }                                                                 \
    }

#define COMPUTE(KA, VB, TBASE)                                            \
    {                                                                     \
        const int base_ = (TBASE);                                        \
        f32x4 sc[8];                                                      \
        _Pragma("unroll")                                                 \
        for (int kb = 0; kb < 8; ++kb) {                                  \
            f32x4 c_ = {0.f, 0.f, 0.f, 0.f};                              \
            c_ = __builtin_amdgcn_mfma_f32_16x16x32_bf16(KA[kb], qh, c_, 0, 0, 0); \
            c_ = __builtin_amdgcn_mfma_f32_16x16x32_bf16(KA[kb], ql, c_, 0, 0, 0); \
            sc[kb] = c_;                                                  \
        }                                                                 \
        if (base_ + KT > cn) {                                            \
            _Pragma("unroll")                                             \
            for (int kb = 0; kb < 8; ++kb)                                \
                _Pragma("unroll")                                         \
                for (int r = 0; r < 4; ++r)                               \
                    if (base_ + kb * 16 + 4 * g + r >= cn) sc[kb][r] = -1e30f; \
        }                                                                 \
        float tm = sc[0][0];                                              \
        _Pragma("unroll")                                                 \
        for (int kb = 0; kb < 8; ++kb)                                    \
            _Pragma("unroll")                                             \
            for (int r = 0; r < 4; ++r) tm = fmaxf(tm, sc[kb][r]);        \
        tm = fmaxf(tm, __shfl_xor(tm, 16));                               \
        tm = fmaxf(tm, __shfl_xor(tm, 32));                               \
        if (__any(tm > m)) {                                              \
            const float mn = fmaxf(m, tm);                                \
            const float alpha = __expf(m - mn);                           \
            m = mn;                                                       \
            l *= alpha;                                                   \
            _Pragma("unroll")                                             \
            for (int r = 0; r < 4; ++r)                                   \
                acc[r] *= __shfl(alpha, 4 * g + r);                       \
        }                                                                 \
        _Pragma("unroll")                                                 \
        for (int kb = 0; kb < 8; ++kb) {                                  \
            const float p0 = __expf(sc[kb][0] - m);                       \
            const float p1 = __expf(sc[kb][1] - m);                       \
            const float p2 = __expf(sc[kb][2] - m);                       \
            const float p3 = __expf(sc[kb][3] - m);                       \
            l += (p0 + p1) + (p2 + p3);                                   \
            const unsigned u01 = (unsigned)f2b(p0) | ((unsigned)f2b(p1) << 16); \
            const unsigned u23 = (unsigned)f2b(p2) | ((unsigned)f2b(p3) << 16); \
            const int s0 = col + 16 * (2 * (g & 1));                      \
            const int s1 = s0 + 16;                                       \
            union { unsigned u[4]; bf16x8 v; } pa;                        \
            pa.u[0] = (unsigned)__shfl((int)u01, s0);                     \
            pa.u[1] = (unsigned)__shfl((int)u23, s0);                     \
            pa.u[2] = (unsigned)__shfl((int)u01, s1);                     \
            pa.u[3] = (unsigned)__shfl((int)u23, s1);                     \
            acc = __builtin_amdgcn_mfma_f32_16x16x32_bf16(pa.v, VB[kb], acc, 0, 0, 0); \
        }                                                                 \
    }

    bf16x8 kaA[8], vbA[8], kaB[8], vbB[8];
    LOADT(kaA, vbA, 0);
    for (int kt = 0; kt < nt; kt += 2) {
        if (kt + 1 < nt) LOADT(kaB, vbB, (kt + 1) * KT);
        COMPUTE(kaA, vbA, kt * KT);
        if (kt + 1 < nt) {
            if (kt + 2 < nt) LOADT(kaA, vbA, (kt + 2) * KT);
            COMPUTE(kaB, vbB, (kt + 1) * KT);
        }
    }
#undef LOADT
#undef COMPUTE

    // l currently per-lane partial: reduce across g-groups (per query col)
    l += __shfl_xor(l, 16);
    l += __shfl_xor(l, 32);

    const float inv = 1.f / l;
    #pragma unroll
    for (int r = 0; r < 4; ++r) {
        const float ir = __shfl(inv, 4 * g + r);
        out[((size_t)(b * S + qrow0 + 4 * g + r)) * E + col * 8 + h] = acc[r] * ir;
    }
}

extern "C" void kernel_launch(void* const* d_in, const int* in_sizes, int n_in,
                              void* d_out, int out_size, void* d_ws, size_t ws_size,
                              hipStream_t stream) {
    int ix = 0, im0 = -1, isc = -1, iw[3] = {-1, -1, -1}, nw = 0;
    for (int i = 0; i < n_in; ++i) {
        const int sz = in_sizes[i];
        if (sz == B * S * E) ix = i;
        else if (sz == B * S) { if (im0 < 0) im0 = i; }
        else if (sz == E * E) { if (nw < 3) iw[nw++] = i; }
        else if (sz == 1 && isc < 0) isc = i;
    }
    if (im0 < 0) im0 = 1;
    if (isc < 0) isc = 3;
    if (nw < 3) { iw[0] = n_in - 3; iw[1] = n_in - 2; iw[2] = n_in - 1; }

    const float* x        = (const float*)d_in[ix];
    const int*   src_mask = (const int*)d_in[im0];
    const int*   masked_p = (const int*)d_in[isc];
    const float* wq       = (const float*)d_in[iw[0]];
    const float* wk       = (const float*)d_in[iw[1]];
    const float* wv       = (const float*)d_in[iw[2]];
    float*       out      = (float*)d_out;

    float*          Qw  = (float*)d_ws;
    unsigned short* Kxg = (unsigned short*)(Qw + (size_t)BH * S * HD);
    unsigned short* Btg = Kxg + (size_t)BH * S * 32;
    int*            pos = (int*)(Btg + (size_t)BH * S * 32);
    int*            cnt = pos + B * S;

    prep<<<BH, 64, 0, stream>>>(src_mask, masked_p, pos, cnt, Kxg, Btg);
    qkv_proj<<<B * S / RPB, 128, 0, stream>>>(x, wq, wk, wv, pos, Qw, Kxg, Btg);
    attn<<<dim3(S / 32, BH), 128, 0, stream>>>(Qw, Kxg, Btg, cnt, out);
}